// Round 1
// baseline (13658.852 us; speedup 1.0000x reference)
//
#include <hip/hip_runtime.h>

// ConditionalSmilesRnn: 3-layer LSTM, B=256, H=1024, steps=99, V=47, P=3.
// Strategy: bf16 MFMA for all GEMMs (f32 accumulate), gx0 GEMM replaced by
// 47-row embedding-gate table + per-batch prop-gate table, LSTM cell fused
// into GEMM epilogue, one kernel per (step, layer), decoder at the end.

typedef unsigned short u16;
typedef __bf16 bf16x8 __attribute__((ext_vector_type(8)));
typedef float f32x4 __attribute__((ext_vector_type(4)));
typedef u16 u16x8 __attribute__((ext_vector_type(8)));

#define MFMA16(a,b,c) __builtin_amdgcn_mfma_f32_16x16x32_bf16((a),(b),(c),0,0,0)

__device__ __forceinline__ u16 f2bf(float f){
  unsigned u = __builtin_bit_cast(unsigned, f);
  u += 0x7fffu + ((u >> 16) & 1u);          // RN-even
  return (u16)(u >> 16);
}
__device__ __forceinline__ float bf2f(u16 s){
  unsigned u = ((unsigned)s) << 16;
  return __builtin_bit_cast(float, u);
}
__device__ __forceinline__ float sigm(float x){ return 1.f/(1.f+__expf(-x)); }
__device__ __forceinline__ float tanhfast(float x){ return 1.f - 2.f/(__expf(2.f*x)+1.f); }

// ---- f32 -> bf16 strided converter (srow % 8 == 0, scalar loads: src rows may be 4B-aligned only)
__global__ void k_conv(const float* __restrict__ src, u16* __restrict__ dst,
                       long total, int srow, int sstride, int dstride, int doff){
  long i = ((long)blockIdx.x*blockDim.x + threadIdx.x)*8;
  if (i >= total) return;
  long r = i / srow;
  int  k = (int)(i - r*srow);
  const float* s = src + r*(long)sstride + k;
  u16x8 o;
  #pragma unroll
  for (int j=0;j<8;++j) o[j] = f2bf(s[j]);
  *(u16x8*)(dst + r*(long)dstride + doff + k) = o;
}

// ---- misc prep: biases, pad-row zeroing, state init, gx_prop
__global__ void k_misc(const float* __restrict__ b_ih0, const float* __restrict__ b_hh0,
                       const float* __restrict__ b_ihr, const float* __restrict__ b_hhr,
                       const float* __restrict__ h0, const float* __restrict__ c0,
                       const float* __restrict__ props, const float* __restrict__ W_ih0,
                       u16* __restrict__ Ebf, u16* __restrict__ Wdec,
                       float* __restrict__ bias0, float* __restrict__ bcat,
                       u16* __restrict__ hbf0, float* __restrict__ cst, float* __restrict__ gxp){
  long i = (long)blockIdx.x*256 + threadIdx.x;
  if (i < 4096){ bias0[i] = b_ih0[i] + b_hh0[i]; return; }
  i -= 4096;
  if (i < 2*4096){ bcat[i] = b_ihr[i] + b_hhr[i]; return; }
  i -= 2*4096;
  if (i < 1024){ Ebf[47*1024 + i] = 0; Wdec[47*1024 + i] = 0; return; }
  i -= 1024;
  if (i < (long)3*256*1024){ hbf0[i] = f2bf(h0[i]); cst[i] = c0[i]; return; }
  i -= (long)3*256*1024;
  if (i < (long)256*4096){
    int b = (int)(i >> 12), n = (int)(i & 4095);
    const float* wr = W_ih0 + (long)n*1027 + 1024;
    gxp[i] = props[b*3+0]*wr[0] + props[b*3+1]*wr[1] + props[b*3+2]*wr[2];
  }
}

// ---- gx_emb[v][n] = sum_k E[v][k] * W_ih0[n][k]  (M=48 padded, N=4096, K=1024)
__global__ __launch_bounds__(64)
void k_gxemb(const u16* __restrict__ Ebf, const u16* __restrict__ Wih0b, float* __restrict__ gxe){
  const int lane = threadIdx.x;
  const int cl = lane & 15, ko = (lane >> 4)*8;
  const int m0 = blockIdx.x*16;          // 3 m-tiles (48 rows)
  const int n0 = blockIdx.y*16;          // 256 n-tiles
  f32x4 acc = {0.f,0.f,0.f,0.f};
  const u16* ap = Ebf   + (size_t)(m0+cl)*1024 + ko;
  const u16* bp = Wih0b + (size_t)(n0+cl)*1024 + ko;
  for (int k0=0; k0<1024; k0+=32){
    bf16x8 a = *(const bf16x8*)(ap + k0);
    bf16x8 b = *(const bf16x8*)(bp + k0);
    acc = MFMA16(a, b, acc);
  }
  const int rbase = (lane >> 4)*4;
  #pragma unroll
  for (int q=0;q<4;++q){
    int v = m0 + rbase + q;
    if (v < 47) gxe[(size_t)v*4096 + n0 + cl] = acc[q];
  }
}

// ---- one LSTM layer, one time step: gates GEMM + fused cell
// LAYER 0: gates = h_prev @ Whh0^T + gx_emb[tok] + gx_prop + bias0
// LAYER 1/2: gates = [x, h_prev] @ Wcat^T + bcat
template<int LAYER>
__global__ __launch_bounds__(128)
void k_step(const u16* __restrict__ xb, const u16* __restrict__ hp,
            u16* __restrict__ hn, float* __restrict__ cst,
            const u16* __restrict__ W, const float* __restrict__ bias,
            const float* __restrict__ gxe, const float* __restrict__ gxp,
            const int* __restrict__ x, int t, u16* __restrict__ outs)
{
  constexpr int KT = (LAYER==0) ? 1024 : 2048;
  const int lane = threadIdx.x & 63;
  const int w    = threadIdx.x >> 6;
  const int cl = lane & 15, ko = (lane >> 4)*8;
  const int m0 = blockIdx.x*32 + w*16;   // 8 m-tiles of 32 rows, 2 waves/WG
  const int j0 = blockIdx.y*32;          // 32 col-tiles of 32 (per gate)

  f32x4 acc[4][2];
  #pragma unroll
  for (int g=0; g<4; ++g)
    #pragma unroll
    for (int hf=0; hf<2; ++hf)
      acc[g][hf] = (f32x4){0.f,0.f,0.f,0.f};

  const u16* wp[4][2];
  #pragma unroll
  for (int g=0; g<4; ++g)
    #pragma unroll
    for (int hf=0; hf<2; ++hf)
      wp[g][hf] = W + (size_t)(g*1024 + j0 + hf*16 + cl)*KT + ko;

  const u16* ah = hp + (size_t)(m0+cl)*1024 + ko;

  if constexpr (LAYER > 0){
    const u16* ax = xb + (size_t)(m0+cl)*1024 + ko;
    #pragma unroll 2
    for (int k0=0; k0<1024; k0+=32){
      bf16x8 a = *(const bf16x8*)(ax + k0);
      #pragma unroll
      for (int g=0; g<4; ++g)
        #pragma unroll
        for (int hf=0; hf<2; ++hf)
          acc[g][hf] = MFMA16(a, *(const bf16x8*)(wp[g][hf] + k0), acc[g][hf]);
    }
    #pragma unroll 2
    for (int k0=0; k0<1024; k0+=32){
      bf16x8 a = *(const bf16x8*)(ah + k0);
      #pragma unroll
      for (int g=0; g<4; ++g)
        #pragma unroll
        for (int hf=0; hf<2; ++hf)
          acc[g][hf] = MFMA16(a, *(const bf16x8*)(wp[g][hf] + 1024 + k0), acc[g][hf]);
    }
  } else {
    #pragma unroll 2
    for (int k0=0; k0<1024; k0+=32){
      bf16x8 a = *(const bf16x8*)(ah + k0);
      #pragma unroll
      for (int g=0; g<4; ++g)
        #pragma unroll
        for (int hf=0; hf<2; ++hf)
          acc[g][hf] = MFMA16(a, *(const bf16x8*)(wp[g][hf] + k0), acc[g][hf]);
    }
  }

  // fused LSTM cell. C/D layout: col = lane&15, row = (lane>>4)*4 + q
  const int rbase = (lane >> 4)*4;
  #pragma unroll
  for (int hf=0; hf<2; ++hf){
    const int col = j0 + hf*16 + cl;
    #pragma unroll
    for (int q=0; q<4; ++q){
      const int row = m0 + rbase + q;           // batch index
      float gi = acc[0][hf][q];
      float gf = acc[1][hf][q];
      float gg = acc[2][hf][q];
      float go = acc[3][hf][q];
      if constexpr (LAYER == 0){
        int tok = (t == 0) ? 1 : x[row*100 + t];
        const float* ge = gxe + (size_t)tok*4096;
        const float* gp = gxp + (size_t)row*4096;
        gi += ge[col]        + gp[col]        + bias[col];
        gf += ge[1024 + col] + gp[1024 + col] + bias[1024 + col];
        gg += ge[2048 + col] + gp[2048 + col] + bias[2048 + col];
        go += ge[3072 + col] + gp[3072 + col] + bias[3072 + col];
      } else {
        gi += bias[col];
        gf += bias[1024 + col];
        gg += bias[2048 + col];
        go += bias[3072 + col];
      }
      float i_ = sigm(gi), f_ = sigm(gf), o_ = sigm(go), g_ = tanhfast(gg);
      size_t off = (size_t)row*1024 + col;
      float cn = f_*cst[off] + i_*g_;
      cst[off] = cn;
      float hv = o_*tanhfast(cn);
      u16 hb = f2bf(hv);
      hn[off] = hb;
      if constexpr (LAYER == 2) outs[off] = hb;
    }
  }
}

// ---- decoder: logits[b,t,v] = outs[t,b,:] . Wdec[v,:] + b_dec[v]
__global__ __launch_bounds__(64)
void k_decode(const u16* __restrict__ outs, const u16* __restrict__ Wdec,
              const float* __restrict__ bdec, float* __restrict__ logits){
  const int lane = threadIdx.x;
  const int cl = lane & 15, ko = (lane >> 4)*8;
  const size_t m0 = (size_t)blockIdx.x*16;       // 1584 m-tiles over 25344 rows
  const u16* ap = outs + (m0+cl)*1024 + ko;
  f32x4 acc[3];
  #pragma unroll
  for (int nt=0; nt<3; ++nt) acc[nt] = (f32x4){0.f,0.f,0.f,0.f};
  const u16* bp = Wdec + (size_t)cl*1024 + ko;
  for (int k0=0; k0<1024; k0+=32){
    bf16x8 a = *(const bf16x8*)(ap + k0);
    #pragma unroll
    for (int nt=0; nt<3; ++nt){
      bf16x8 b = *(const bf16x8*)(bp + (size_t)nt*16*1024 + k0);
      acc[nt] = MFMA16(a, b, acc[nt]);
    }
  }
  const int rbase = (lane >> 4)*4;
  #pragma unroll
  for (int nt=0; nt<3; ++nt){
    #pragma unroll
    for (int q=0; q<4; ++q){
      int v = nt*16 + cl;
      if (v < 47){
        size_t row = m0 + rbase + q;   // row = t*256 + b
        int tt = (int)(row >> 8);
        int b  = (int)(row & 255);
        logits[((size_t)b*99 + tt)*47 + v] = acc[nt][q] + bdec[v];
      }
    }
  }
}

// ---- final hT / cT copy-out
__global__ void k_final(const u16* __restrict__ hb, const float* __restrict__ cst, float* __restrict__ out){
  int i = blockIdx.x*256 + threadIdx.x;
  if (i < 3*256*1024){
    out[1191168 + i]          = bf2f(hb[i]);
    out[1191168 + 786432 + i] = cst[i];
  }
}

extern "C" void kernel_launch(void* const* d_in, const int* in_sizes, int n_in,
                              void* d_out, int out_size, void* d_ws, size_t ws_size,
                              hipStream_t stream) {
  (void)in_sizes; (void)n_in; (void)out_size; (void)ws_size;
  const int*   x      = (const int*)  d_in[0];
  const float* props  = (const float*)d_in[1];
  const float* h0     = (const float*)d_in[2];
  const float* c0     = (const float*)d_in[3];
  const float* E      = (const float*)d_in[4];
  const float* W_ih0  = (const float*)d_in[5];
  const float* W_hh0  = (const float*)d_in[6];
  const float* b_ih0  = (const float*)d_in[7];
  const float* b_hh0  = (const float*)d_in[8];
  const float* W_ih_r = (const float*)d_in[9];
  const float* W_hh_r = (const float*)d_in[10];
  const float* b_ih_r = (const float*)d_in[11];
  const float* b_hh_r = (const float*)d_in[12];
  const float* W_dec  = (const float*)d_in[13];
  const float* b_dec  = (const float*)d_in[14];
  float* out = (float*)d_out;

  // workspace layout (~109 MB)
  u16* Whh0  = (u16*)d_ws;                          // 4096*1024
  u16* Wcat  = Whh0  + (size_t)4096*1024;           // 2*4096*2048  ([W_ih_r | W_hh_r] rows)
  u16* Wdec  = Wcat  + (size_t)2*4096*2048;         // 48*1024 (row 47 = 0)
  u16* Wih0b = Wdec  + (size_t)48*1024;             // 4096*1024 (first 1024 cols of W_ih0)
  u16* Ebf   = Wih0b + (size_t)4096*1024;           // 48*1024 (row 47 = 0)
  u16* hbf   = Ebf   + (size_t)48*1024;             // 2 * 3*256*1024 (double-buffered h, bf16)
  u16* outsb = hbf   + (size_t)2*3*256*1024;        // 99*256*1024 (top-layer h per step)
  float* gxe   = (float*)(outsb + (size_t)99*256*1024); // 47*4096
  float* gxp   = gxe   + (size_t)47*4096;               // 256*4096
  float* bias0 = gxp   + (size_t)256*4096;              // 4096
  float* bcat  = bias0 + 4096;                          // 2*4096
  float* cst   = bcat  + 2*4096;                        // 3*256*1024 (f32 cell state)

  // ---- prep
  k_conv<<<2048, 256, 0, stream>>>(W_hh0,  Whh0,  (long)4096*1024, 1024, 1024, 1024, 0);
  k_conv<<<4096, 256, 0, stream>>>(W_ih_r, Wcat,  (long)8192*1024, 1024, 1024, 2048, 0);
  k_conv<<<4096, 256, 0, stream>>>(W_hh_r, Wcat,  (long)8192*1024, 1024, 1024, 2048, 1024);
  k_conv<<<2048, 256, 0, stream>>>(W_ih0,  Wih0b, (long)4096*1024, 1024, 1027, 1024, 0);
  k_conv<<<24,   256, 0, stream>>>(E,      Ebf,   (long)47*1024,   1024, 1024, 1024, 0);
  k_conv<<<24,   256, 0, stream>>>(W_dec,  Wdec,  (long)47*1024,   1024, 1024, 1024, 0);
  k_misc<<<7221, 256, 0, stream>>>(b_ih0, b_hh0, b_ih_r, b_hh_r, h0, c0, props, W_ih0,
                                   Ebf, Wdec, bias0, bcat, hbf, cst, gxp);
  k_gxemb<<<dim3(3,256), 64, 0, stream>>>(Ebf, Wih0b, gxe);

  // ---- recurrence
  const size_t BH = (size_t)256*1024;
  for (int t = 0; t < 99; ++t){
    int p = t & 1;
    u16* cur = hbf + (size_t)p*3*BH;       // state at step t-1
    u16* nxt = hbf + (size_t)(p^1)*3*BH;   // state at step t (written now)
    k_step<0><<<dim3(8,32), 128, 0, stream>>>(nullptr, cur, nxt, cst,
                                              Whh0, bias0, gxe, gxp, x, t, nullptr);
    k_step<1><<<dim3(8,32), 128, 0, stream>>>(nxt, cur + BH, nxt + BH, cst + BH,
                                              Wcat, bcat, nullptr, nullptr, nullptr, t, nullptr);
    k_step<2><<<dim3(8,32), 128, 0, stream>>>(nxt + BH, cur + 2*BH, nxt + 2*BH, cst + 2*BH,
                                              Wcat + (size_t)4096*2048, bcat + 4096,
                                              nullptr, nullptr, nullptr, t,
                                              outsb + (size_t)t*BH);
  }

  // ---- decode + final states (after 99 steps, final h is in buffer 1)
  k_decode<<<1584, 64, 0, stream>>>(outsb, Wdec, b_dec, out);
  k_final<<<3072, 256, 0, stream>>>(hbf + 3*BH, cst, out);
}

// Round 2
// 11062.540 us; speedup vs baseline: 1.2347x; 1.2347x over previous
//
#include <hip/hip_runtime.h>

// ConditionalSmilesRnn: 3-layer LSTM, B=256, H=1024, steps=99, V=47, P=3.
// R2: diagonal wavefront fusion — one dispatch computes (L0@t, L1@t-1, L2@t-2).
// 101 dispatches instead of 297; 3x parallelism per dispatch; TM=64/TJ=32
// tiles (4-wave WGs, wave = 16 rows x 4 gates x 32 cols).

typedef unsigned short u16;
typedef __bf16 bf16x8 __attribute__((ext_vector_type(8)));
typedef float f32x4 __attribute__((ext_vector_type(4)));
typedef u16 u16x8 __attribute__((ext_vector_type(8)));

#define MFMA16(a,b,c) __builtin_amdgcn_mfma_f32_16x16x32_bf16((a),(b),(c),0,0,0)

__device__ __forceinline__ u16 f2bf(float f){
  unsigned u = __builtin_bit_cast(unsigned, f);
  u += 0x7fffu + ((u >> 16) & 1u);          // RN-even
  return (u16)(u >> 16);
}
__device__ __forceinline__ float bf2f(u16 s){
  unsigned u = ((unsigned)s) << 16;
  return __builtin_bit_cast(float, u);
}
__device__ __forceinline__ float sigm(float x){ return 1.f/(1.f+__expf(-x)); }
__device__ __forceinline__ float tanhfast(float x){ return 1.f - 2.f/(__expf(2.f*x)+1.f); }

// ---- f32 -> bf16 strided converter
__global__ void k_conv(const float* __restrict__ src, u16* __restrict__ dst,
                       long total, int srow, int sstride, int dstride, int doff){
  long i = ((long)blockIdx.x*blockDim.x + threadIdx.x)*8;
  if (i >= total) return;
  long r = i / srow;
  int  k = (int)(i - r*srow);
  const float* s = src + r*(long)sstride + k;
  u16x8 o;
  #pragma unroll
  for (int j=0;j<8;++j) o[j] = f2bf(s[j]);
  *(u16x8*)(dst + r*(long)dstride + doff + k) = o;
}

// ---- misc prep: biases, pad-row zeroing, state init, gx_prop
__global__ void k_misc(const float* __restrict__ b_ih0, const float* __restrict__ b_hh0,
                       const float* __restrict__ b_ihr, const float* __restrict__ b_hhr,
                       const float* __restrict__ h0, const float* __restrict__ c0,
                       const float* __restrict__ props, const float* __restrict__ W_ih0,
                       u16* __restrict__ Ebf, u16* __restrict__ Wdec,
                       float* __restrict__ bias0, float* __restrict__ bcat,
                       u16* __restrict__ hbf0, float* __restrict__ cst, float* __restrict__ gxp){
  long i = (long)blockIdx.x*256 + threadIdx.x;
  if (i < 4096){ bias0[i] = b_ih0[i] + b_hh0[i]; return; }
  i -= 4096;
  if (i < 2*4096){ bcat[i] = b_ihr[i] + b_hhr[i]; return; }
  i -= 2*4096;
  if (i < 1024){ Ebf[47*1024 + i] = 0; Wdec[47*1024 + i] = 0; return; }
  i -= 1024;
  if (i < (long)3*256*1024){ hbf0[i] = f2bf(h0[i]); cst[i] = c0[i]; return; }
  i -= (long)3*256*1024;
  if (i < (long)256*4096){
    int b = (int)(i >> 12), n = (int)(i & 4095);
    const float* wr = W_ih0 + (long)n*1027 + 1024;
    gxp[i] = props[b*3+0]*wr[0] + props[b*3+1]*wr[1] + props[b*3+2]*wr[2];
  }
}

// ---- gx_emb[v][n] = sum_k E[v][k] * W_ih0[n][k]  (M=48 padded, N=4096, K=1024)
__global__ __launch_bounds__(64)
void k_gxemb(const u16* __restrict__ Ebf, const u16* __restrict__ Wih0b, float* __restrict__ gxe){
  const int lane = threadIdx.x;
  const int cl = lane & 15, ko = (lane >> 4)*8;
  const int m0 = blockIdx.x*16;
  const int n0 = blockIdx.y*16;
  f32x4 acc = {0.f,0.f,0.f,0.f};
  const u16* ap = Ebf   + (size_t)(m0+cl)*1024 + ko;
  const u16* bp = Wih0b + (size_t)(n0+cl)*1024 + ko;
  for (int k0=0; k0<1024; k0+=32){
    bf16x8 a = *(const bf16x8*)(ap + k0);
    bf16x8 b = *(const bf16x8*)(bp + k0);
    acc = MFMA16(a, b, acc);
  }
  const int rbase = (lane >> 4)*4;
  #pragma unroll
  for (int q=0;q<4;++q){
    int v = m0 + rbase + q;
    if (v < 47) gxe[(size_t)v*4096 + n0 + cl] = acc[q];
  }
}

// ---- diagonal dispatch: (L0@d, L1@d-1, L2@d-2) fused; one layer-step per blockIdx.y
// layer 0: gates = h_prev @ Whh0^T + gxe[tok] + gxp + bias0   (K=1024)
// layer 1/2: gates = [x, h_prev] @ Wcat_l^T + bcat_l          (K=2048)
// WG: 256 threads = 4 waves; wave = 16 rows x (4 gates x 32 cols); TM=64, TJ=32.
__global__ __launch_bounds__(256, 2)
void k_diag(int d, const int* __restrict__ x, u16* __restrict__ hbf,
            u16* __restrict__ outsb, float* __restrict__ cst,
            const u16* __restrict__ Whh0, const u16* __restrict__ Wcat,
            const float* __restrict__ bias0, const float* __restrict__ bcat,
            const float* __restrict__ gxe, const float* __restrict__ gxp)
{
  const int layer = blockIdx.y;
  const int t = d - layer;
  if (t < 0 || t >= 99) return;
  const size_t BH = (size_t)256*1024;

  const int bx = blockIdx.x;            // 128 = 4 mt x 32 jt; bx = mt*32 + jt
  const int mt = bx >> 5, jt = bx & 31; //   (mt-copies 32 apart -> same XCD)
  const int lane = threadIdx.x & 63, w = threadIdx.x >> 6;
  const int cl = lane & 15, ko = (lane >> 4)*8;
  const int m0 = mt*64 + w*16;
  const int j0 = jt*32;
  const int p = t & 1;

  const u16* hp = hbf + ((size_t)p*3 + layer)*BH;       // own state @ t-1
  u16*       hn = hbf + ((size_t)(p^1)*3 + layer)*BH;   // own state @ t
  float*     cc = cst + (size_t)layer*BH;

  f32x4 acc[4][2];
  #pragma unroll
  for (int g=0; g<4; ++g)
    #pragma unroll
    for (int s=0; s<2; ++s)
      acc[g][s] = (f32x4){0.f,0.f,0.f,0.f};

  const u16* ah = hp + (size_t)(m0+cl)*1024 + ko;

  if (layer == 0){
    const u16* wp[4][2];
    #pragma unroll
    for (int g=0; g<4; ++g)
      #pragma unroll
      for (int s=0; s<2; ++s)
        wp[g][s] = Whh0 + (size_t)(g*1024 + j0 + s*16 + cl)*1024 + ko;
    #pragma unroll 2
    for (int k0=0; k0<1024; k0+=32){
      bf16x8 a = *(const bf16x8*)(ah + k0);
      #pragma unroll
      for (int g=0; g<4; ++g)
        #pragma unroll
        for (int s=0; s<2; ++s)
          acc[g][s] = MFMA16(a, *(const bf16x8*)(wp[g][s] + k0), acc[g][s]);
    }
  } else {
    const u16* W  = Wcat + (size_t)(layer-1)*4096*2048;
    const u16* xb = hbf + ((size_t)(p^1)*3 + (layer-1))*BH;  // lower layer's h @ t (this dispatch's d-? no: written last dispatch)
    const u16* ax = xb + (size_t)(m0+cl)*1024 + ko;
    const u16* wp[4][2];
    #pragma unroll
    for (int g=0; g<4; ++g)
      #pragma unroll
      for (int s=0; s<2; ++s)
        wp[g][s] = W + (size_t)(g*1024 + j0 + s*16 + cl)*2048 + ko;
    #pragma unroll 2
    for (int k0=0; k0<1024; k0+=32){
      bf16x8 a = *(const bf16x8*)(ax + k0);
      #pragma unroll
      for (int g=0; g<4; ++g)
        #pragma unroll
        for (int s=0; s<2; ++s)
          acc[g][s] = MFMA16(a, *(const bf16x8*)(wp[g][s] + k0), acc[g][s]);
    }
    #pragma unroll 2
    for (int k0=0; k0<1024; k0+=32){
      bf16x8 a = *(const bf16x8*)(ah + k0);
      #pragma unroll
      for (int g=0; g<4; ++g)
        #pragma unroll
        for (int s=0; s<2; ++s)
          acc[g][s] = MFMA16(a, *(const bf16x8*)(wp[g][s] + 1024 + k0), acc[g][s]);
    }
  }

  // fused LSTM cell. C/D layout: col = lane&15, row = (lane>>4)*4 + q
  const int rbase = (lane >> 4)*4;
  const float* bias = (layer == 0) ? bias0 : bcat + (size_t)(layer-1)*4096;
  #pragma unroll
  for (int s=0; s<2; ++s){
    const int col = j0 + s*16 + cl;
    #pragma unroll
    for (int q=0; q<4; ++q){
      const int row = m0 + rbase + q;           // batch index
      float gi = acc[0][s][q] + bias[col];
      float gf = acc[1][s][q] + bias[1024 + col];
      float gg = acc[2][s][q] + bias[2048 + col];
      float go = acc[3][s][q] + bias[3072 + col];
      if (layer == 0){
        int tok = (t == 0) ? 1 : x[row*100 + t];
        const float* ge = gxe + (size_t)tok*4096;
        const float* gp = gxp + (size_t)row*4096;
        gi += ge[col]        + gp[col];
        gf += ge[1024 + col] + gp[1024 + col];
        gg += ge[2048 + col] + gp[2048 + col];
        go += ge[3072 + col] + gp[3072 + col];
      }
      float i_ = sigm(gi), f_ = sigm(gf), o_ = sigm(go), g_ = tanhfast(gg);
      size_t off = (size_t)row*1024 + col;
      float cn = f_*cc[off] + i_*g_;
      cc[off] = cn;
      float hv = o_*tanhfast(cn);
      u16 hb = f2bf(hv);
      hn[off] = hb;
      if (layer == 2) outsb[(size_t)t*BH + off] = hb;
    }
  }
}

// ---- decoder: logits[b,t,v] = outs[t,b,:] . Wdec[v,:] + b_dec[v]
__global__ __launch_bounds__(256)
void k_decode(const u16* __restrict__ outs, const u16* __restrict__ Wdec,
              const float* __restrict__ bdec, float* __restrict__ logits){
  const int lane = threadIdx.x & 63, w = threadIdx.x >> 6;
  const int cl = lane & 15, ko = (lane >> 4)*8;
  const size_t m0 = ((size_t)blockIdx.x*4 + w)*16;   // 396 WGs x 4 waves over 25344 rows
  const u16* ap = outs + (m0+cl)*1024 + ko;
  f32x4 acc[3];
  #pragma unroll
  for (int nt=0; nt<3; ++nt) acc[nt] = (f32x4){0.f,0.f,0.f,0.f};
  const u16* bp = Wdec + (size_t)cl*1024 + ko;
  for (int k0=0; k0<1024; k0+=32){
    bf16x8 a = *(const bf16x8*)(ap + k0);
    #pragma unroll
    for (int nt=0; nt<3; ++nt){
      bf16x8 b = *(const bf16x8*)(bp + (size_t)nt*16*1024 + k0);
      acc[nt] = MFMA16(a, b, acc[nt]);
    }
  }
  const int rbase = (lane >> 4)*4;
  #pragma unroll
  for (int nt=0; nt<3; ++nt){
    #pragma unroll
    for (int q=0; q<4; ++q){
      int v = nt*16 + cl;
      if (v < 47){
        size_t row = m0 + rbase + q;   // row = t*256 + b
        int tt = (int)(row >> 8);
        int b  = (int)(row & 255);
        logits[((size_t)b*99 + tt)*47 + v] = acc[nt][q] + bdec[v];
      }
    }
  }
}

// ---- final hT / cT copy-out
__global__ void k_final(const u16* __restrict__ hb, const float* __restrict__ cst, float* __restrict__ out){
  int i = blockIdx.x*256 + threadIdx.x;
  if (i < 3*256*1024){
    out[1191168 + i]          = bf2f(hb[i]);
    out[1191168 + 786432 + i] = cst[i];
  }
}

extern "C" void kernel_launch(void* const* d_in, const int* in_sizes, int n_in,
                              void* d_out, int out_size, void* d_ws, size_t ws_size,
                              hipStream_t stream) {
  (void)in_sizes; (void)n_in; (void)out_size; (void)ws_size;
  const int*   x      = (const int*)  d_in[0];
  const float* props  = (const float*)d_in[1];
  const float* h0     = (const float*)d_in[2];
  const float* c0     = (const float*)d_in[3];
  const float* E      = (const float*)d_in[4];
  const float* W_ih0  = (const float*)d_in[5];
  const float* W_hh0  = (const float*)d_in[6];
  const float* b_ih0  = (const float*)d_in[7];
  const float* b_hh0  = (const float*)d_in[8];
  const float* W_ih_r = (const float*)d_in[9];
  const float* W_hh_r = (const float*)d_in[10];
  const float* b_ih_r = (const float*)d_in[11];
  const float* b_hh_r = (const float*)d_in[12];
  const float* W_dec  = (const float*)d_in[13];
  const float* b_dec  = (const float*)d_in[14];
  float* out = (float*)d_out;

  // workspace layout (~109 MB)
  u16* Whh0  = (u16*)d_ws;                          // 4096*1024
  u16* Wcat  = Whh0  + (size_t)4096*1024;           // 2*4096*2048  ([W_ih_r | W_hh_r] rows)
  u16* Wdec  = Wcat  + (size_t)2*4096*2048;         // 48*1024 (row 47 = 0)
  u16* Wih0b = Wdec  + (size_t)48*1024;             // 4096*1024 (first 1024 cols of W_ih0)
  u16* Ebf   = Wih0b + (size_t)4096*1024;           // 48*1024 (row 47 = 0)
  u16* hbf   = Ebf   + (size_t)48*1024;             // 2 * 3*256*1024 (double-buffered h, bf16)
  u16* outsb = hbf   + (size_t)2*3*256*1024;        // 99*256*1024 (top-layer h per step)
  float* gxe   = (float*)(outsb + (size_t)99*256*1024); // 47*4096
  float* gxp   = gxe   + (size_t)47*4096;               // 256*4096
  float* bias0 = gxp   + (size_t)256*4096;              // 4096
  float* bcat  = bias0 + 4096;                          // 2*4096
  float* cst   = bcat  + 2*4096;                        // 3*256*1024 (f32 cell state)

  // ---- prep
  k_conv<<<2048, 256, 0, stream>>>(W_hh0,  Whh0,  (long)4096*1024, 1024, 1024, 1024, 0);
  k_conv<<<4096, 256, 0, stream>>>(W_ih_r, Wcat,  (long)8192*1024, 1024, 1024, 2048, 0);
  k_conv<<<4096, 256, 0, stream>>>(W_hh_r, Wcat,  (long)8192*1024, 1024, 1024, 2048, 1024);
  k_conv<<<2048, 256, 0, stream>>>(W_ih0,  Wih0b, (long)4096*1024, 1024, 1027, 1024, 0);
  k_conv<<<24,   256, 0, stream>>>(E,      Ebf,   (long)47*1024,   1024, 1024, 1024, 0);
  k_conv<<<24,   256, 0, stream>>>(W_dec,  Wdec,  (long)47*1024,   1024, 1024, 1024, 0);
  k_misc<<<7221, 256, 0, stream>>>(b_ih0, b_hh0, b_ih_r, b_hh_r, h0, c0, props, W_ih0,
                                   Ebf, Wdec, bias0, bcat, hbf, cst, gxp);
  k_gxemb<<<dim3(3,256), 64, 0, stream>>>(Ebf, Wih0b, gxe);

  // ---- diagonal recurrence: dispatch d runs (L0@d, L1@d-1, L2@d-2)
  for (int d = 0; d < 101; ++d){
    k_diag<<<dim3(128, 3), 256, 0, stream>>>(d, x, hbf, outsb, cst,
                                             Whh0, Wcat, bias0, bcat, gxe, gxp);
  }

  // ---- decode + final states (all layers end at t=98 -> state buffer 1)
  k_decode<<<396, 256, 0, stream>>>(outsb, Wdec, b_dec, out);
  k_final<<<3072, 256, 0, stream>>>(hbf + (size_t)3*256*1024, cst, out);
}

// Round 3
// 4093.428 us; speedup vs baseline: 3.3368x; 2.7025x over previous
//
#include <hip/hip_runtime.h>

// ConditionalSmilesRnn: 3-layer LSTM, B=256, H=1024, steps=99, V=47, P=3.
// R3: diag-fused dispatches with LDS double-buffered staging (global_load_lds
// width16, counted vmcnt, raw s_barrier), gate-interleaved weight layout
// (tile of 64 weight rows = 16 hidden cols x 4 gates -> shuffle-free cell),
// XCD-pinned block mapping so weight slices stay L2-resident across steps.

typedef unsigned short u16;
typedef __bf16 bf16x8 __attribute__((ext_vector_type(8)));
typedef float f32x4 __attribute__((ext_vector_type(4)));
typedef u16 u16x8 __attribute__((ext_vector_type(8)));

#define MFMA16(a,b,c) __builtin_amdgcn_mfma_f32_16x16x32_bf16((a),(b),(c),0,0,0)

__device__ __forceinline__ u16 f2bf(float f){
  unsigned u = __builtin_bit_cast(unsigned, f);
  u += 0x7fffu + ((u >> 16) & 1u);          // RN-even
  return (u16)(u >> 16);
}
__device__ __forceinline__ float bf2f(u16 s){
  unsigned u = ((unsigned)s) << 16;
  return __builtin_bit_cast(float, u);
}
__device__ __forceinline__ float sigm(float x){ return 1.f/(1.f+__expf(-x)); }
__device__ __forceinline__ float tanhfast(float x){ return 1.f - 2.f/(__expf(2.f*x)+1.f); }

__device__ __forceinline__ void ld_lds16(const u16* g, u16* l){
  __builtin_amdgcn_global_load_lds((const __attribute__((address_space(1))) void*)g,
                                   (__attribute__((address_space(3))) void*)l, 16, 0, 0);
}

// ---- f32 -> bf16 strided converter
__global__ void k_conv(const float* __restrict__ src, u16* __restrict__ dst,
                       long total, int srow, int sstride, int dstride, int doff){
  long i = ((long)blockIdx.x*blockDim.x + threadIdx.x)*8;
  if (i >= total) return;
  long r = i / srow;
  int  k = (int)(i - r*srow);
  const float* s = src + r*(long)sstride + k;
  u16x8 o;
  #pragma unroll
  for (int j=0;j<8;++j) o[j] = f2bf(s[j]);
  *(u16x8*)(dst + r*(long)dstride + doff + k) = o;
}

// ---- L0 weight repack: dst[n'][k] = bf16(W_hh0[n][k])
// n = g*1024 + h;  n' = (h/16)*64 + g*16 + (h%16)
__global__ void k_repack0(const float* __restrict__ src, u16* __restrict__ dst){
  long i = ((long)blockIdx.x*256 + threadIdx.x)*8;   // over 4096*1024
  int np = (int)(i >> 10), k = (int)(i & 1023);
  int hblk = np >> 6, g = (np >> 4) & 3, hlo = np & 15;
  int n = g*1024 + hblk*16 + hlo;
  const float* s = src + (long)n*1024 + k;
  u16x8 o;
  #pragma unroll
  for (int j=0;j<8;++j) o[j] = f2bf(s[j]);
  *(u16x8*)(dst + (long)np*1024 + k) = o;
}

// ---- L1/2 weight repack: dst[l][n'][0:1024]=W_ih_r[l][n], [1024:2048]=W_hh_r[l][n]
__global__ void k_repack12(const float* __restrict__ Wih, const float* __restrict__ Whh,
                           u16* __restrict__ dst){
  long i = ((long)blockIdx.x*256 + threadIdx.x)*8;   // over 2*4096*2048
  long l = i >> 23;
  long r = i & 8388607;
  int np = (int)(r >> 11), k = (int)(r & 2047);
  int hblk = np >> 6, g = (np >> 4) & 3, hlo = np & 15;
  int n = g*1024 + hblk*16 + hlo;
  const float* s = (k < 1024) ? Wih + ((long)l*4096 + n)*1024 + k
                              : Whh + ((long)l*4096 + n)*1024 + (k - 1024);
  u16x8 o;
  #pragma unroll
  for (int j=0;j<8;++j) o[j] = f2bf(s[j]);
  *(u16x8*)(dst + ((long)l*4096 + np)*2048 + k) = o;
}

// ---- misc prep: biases, pad-row zeroing, state init, gx_prop
__global__ void k_misc(const float* __restrict__ b_ih0, const float* __restrict__ b_hh0,
                       const float* __restrict__ b_ihr, const float* __restrict__ b_hhr,
                       const float* __restrict__ h0, const float* __restrict__ c0,
                       const float* __restrict__ props, const float* __restrict__ W_ih0,
                       u16* __restrict__ Ebf, u16* __restrict__ Wdec,
                       float* __restrict__ bias0, float* __restrict__ bcat,
                       u16* __restrict__ hbf0, float* __restrict__ cst, float* __restrict__ gxp){
  long i = (long)blockIdx.x*256 + threadIdx.x;
  if (i < 4096){ bias0[i] = b_ih0[i] + b_hh0[i]; return; }
  i -= 4096;
  if (i < 2*4096){ bcat[i] = b_ihr[i] + b_hhr[i]; return; }
  i -= 2*4096;
  if (i < 1024){ Ebf[47*1024 + i] = 0; Wdec[47*1024 + i] = 0; return; }
  i -= 1024;
  if (i < (long)3*256*1024){ hbf0[i] = f2bf(h0[i]); cst[i] = c0[i]; return; }
  i -= (long)3*256*1024;
  if (i < (long)256*4096){
    int b = (int)(i >> 12), n = (int)(i & 4095);
    const float* wr = W_ih0 + (long)n*1027 + 1024;
    gxp[i] = props[b*3+0]*wr[0] + props[b*3+1]*wr[1] + props[b*3+2]*wr[2];
  }
}

// ---- gx_emb[v][n] = sum_k E[v][k] * W_ih0[n][k]  (M=48 padded, N=4096, K=1024)
__global__ __launch_bounds__(64)
void k_gxemb(const u16* __restrict__ Ebf, const u16* __restrict__ Wih0b, float* __restrict__ gxe){
  const int lane = threadIdx.x;
  const int cl = lane & 15, ko = (lane >> 4)*8;
  const int m0 = blockIdx.x*16;
  const int n0 = blockIdx.y*16;
  f32x4 acc = {0.f,0.f,0.f,0.f};
  const u16* ap = Ebf   + (size_t)(m0+cl)*1024 + ko;
  const u16* bp = Wih0b + (size_t)(n0+cl)*1024 + ko;
  for (int k0=0; k0<1024; k0+=32){
    bf16x8 a = *(const bf16x8*)(ap + k0);
    bf16x8 b = *(const bf16x8*)(bp + k0);
    acc = MFMA16(a, b, acc);
  }
  const int rbase = (lane >> 4)*4;
  #pragma unroll
  for (int q=0;q<4;++q){
    int v = m0 + rbase + q;
    if (v < 47) gxe[(size_t)v*4096 + n0 + cl] = acc[q];
  }
}

// ---- one tile of one (layer, t): TM=128 x TN=64, K = 1024/2048, BK=64.
// 4 waves, wave = 32m x 64n; 64 weight rows = 16 hidden cols x 4 gates.
template<int LAYER>
__device__ __forceinline__ void diag_tile(int mt, int jt, int t,
    const int* __restrict__ x, u16* __restrict__ hbf, u16* __restrict__ outsb,
    float* __restrict__ cst, const u16* __restrict__ Wre0, const u16* __restrict__ Wre12,
    const float* __restrict__ bias0, const float* __restrict__ bcat,
    const float* __restrict__ gxe, const float* __restrict__ gxp, u16* lds)
{
  constexpr int KT = (LAYER==0) ? 1024 : 2048;
  constexpr int NT = KT/64;
  const int tid = threadIdx.x;
  const int lane = tid & 63, w = tid >> 6;
  const int cl = lane & 15, hi = lane >> 4;
  const size_t BH = (size_t)256*1024;
  const int p = t & 1;

  const u16* hp = hbf + ((size_t)p*3 + LAYER)*BH;       // own h @ t-1
  u16*       hn = hbf + ((size_t)(p^1)*3 + LAYER)*BH;   // own h @ t
  float*     cc = cst + (size_t)LAYER*BH;
  const u16* xb = (LAYER>0) ? hbf + ((size_t)(p^1)*3 + (LAYER-1))*BH : (const u16*)0;
  const u16* Bsrc = (LAYER==0 ? Wre0 : Wre12 + (size_t)(LAYER-1)*4096*2048)
                    + (size_t)jt*64*KT;
  const int m_base = mt*128;
  const int m0w = w*32;

  u16* sA[2] = { lds,         lds + 8192  };   // 128 rows x 64 (x2)
  u16* sB[2] = { lds + 16384, lds + 20480 };   // 64 rows x 64 (x2)

  auto stage = [&](int buf, int kt){
    const int kbase = kt*64;
    #pragma unroll
    for (int j=0; j<4; ++j){                   // A: 1024 granules / 256 thr
      int G = j*256 + tid;
      int r = G >> 3;
      int kk = kbase + (((G & 7) ^ (r & 7)) << 3);   // src pre-swizzle
      const u16* src;
      if (LAYER > 0)
        src = (kbase < 1024) ? xb + (size_t)(m_base+r)*1024 + kk
                             : hp + (size_t)(m_base+r)*1024 + (kk - 1024);
      else
        src = hp + (size_t)(m_base+r)*1024 + kk;
      ld_lds16(src, sA[buf] + (size_t)G*8);
    }
    #pragma unroll
    for (int j=0; j<2; ++j){                   // B: 512 granules / 256 thr
      int G = j*256 + tid;
      int r = G >> 3;
      int kk = kbase + (((G & 7) ^ (r & 7)) << 3);
      ld_lds16(Bsrc + (size_t)r*KT + kk, sB[buf] + (size_t)G*8);
    }
  };

  f32x4 acc[2][4];
  #pragma unroll
  for (int mf=0; mf<2; ++mf)
    #pragma unroll
    for (int g=0; g<4; ++g)
      acc[mf][g] = (f32x4){0.f,0.f,0.f,0.f};

  stage(0, 0);
  for (int kt=0; kt<NT; ++kt){
    const int cur = kt & 1;
    if (kt+1 < NT){ stage(cur^1, kt+1); asm volatile("s_waitcnt vmcnt(6)" ::: "memory"); }
    else          {                     asm volatile("s_waitcnt vmcnt(0)" ::: "memory"); }
    __builtin_amdgcn_s_barrier();
    asm volatile("" ::: "memory");
    const u16* A = sA[cur];
    const u16* B = sB[cur];
    #pragma unroll
    for (int half=0; half<2; ++half){
      const int kg = half*4 + hi;              // granule index (swizzled read)
      bf16x8 a0, a1, b[4];
      { int r = m0w + cl;      a0 = *(const bf16x8*)(A + r*64 + ((kg ^ (r&7))<<3)); }
      { int r = m0w + 16 + cl; a1 = *(const bf16x8*)(A + r*64 + ((kg ^ (r&7))<<3)); }
      #pragma unroll
      for (int g=0; g<4; ++g){
        int r = g*16 + cl;
        b[g] = *(const bf16x8*)(B + r*64 + ((kg ^ (r&7))<<3));
      }
      #pragma unroll
      for (int g=0; g<4; ++g){
        acc[0][g] = MFMA16(a0, b[g], acc[0][g]);
        acc[1][g] = MFMA16(a1, b[g], acc[1][g]);
      }
    }
    asm volatile("" ::: "memory");
    __builtin_amdgcn_s_barrier();
  }

  // fused LSTM cell. C/D: col = cl (-> gate g, hcol), row = hi*4+q (-> batch)
  const int hcol = jt*16 + cl;
  const float* bias = (LAYER==0) ? bias0 : bcat + (size_t)(LAYER-1)*4096;
  const float bi_ = bias[hcol], bf_ = bias[1024+hcol],
              bg_ = bias[2048+hcol], bo_ = bias[3072+hcol];
  #pragma unroll
  for (int mf=0; mf<2; ++mf){
    #pragma unroll
    for (int q=0; q<4; ++q){
      const int row = m_base + m0w + mf*16 + hi*4 + q;
      float gi = acc[mf][0][q] + bi_;
      float gf = acc[mf][1][q] + bf_;
      float gg = acc[mf][2][q] + bg_;
      float go = acc[mf][3][q] + bo_;
      if (LAYER == 0){
        const int tok = (t==0) ? 1 : x[row*100 + t];
        const float* ge = gxe + (size_t)tok*4096;
        const float* gp = gxp + (size_t)row*4096;
        gi += ge[hcol]        + gp[hcol];
        gf += ge[1024 + hcol] + gp[1024 + hcol];
        gg += ge[2048 + hcol] + gp[2048 + hcol];
        go += ge[3072 + hcol] + gp[3072 + hcol];
      }
      const float i_ = sigm(gi), f_ = sigm(gf), o_ = sigm(go), g_ = tanhfast(gg);
      const size_t off = (size_t)row*1024 + hcol;
      const float cn = f_*cc[off] + i_*g_;
      cc[off] = cn;
      const u16 hb = f2bf(o_*tanhfast(cn));
      hn[off] = hb;
      if (LAYER == 2) outsb[(size_t)t*BH + off] = hb;
    }
  }
}

// grid = 384: id = slot + 192*mt; slot = layer*64 + jt  (xcd = slot%8, stable
// across dispatches -> each XCD re-reads the same ~5MB weight slice)
__global__ __launch_bounds__(256)
void k_diag(int d, const int* __restrict__ x, u16* __restrict__ hbf,
            u16* __restrict__ outsb, float* __restrict__ cst,
            const u16* __restrict__ Wre0, const u16* __restrict__ Wre12,
            const float* __restrict__ bias0, const float* __restrict__ bcat,
            const float* __restrict__ gxe, const float* __restrict__ gxp)
{
  __shared__ u16 lds[24576];
  const int id = blockIdx.x;
  const int mt = id / 192;
  const int slot = id - mt*192;
  const int layer = slot >> 6;
  const int jt = slot & 63;
  const int t = d - layer;
  if (t < 0 || t >= 99) return;
  if (layer == 0)
    diag_tile<0>(mt, jt, t, x, hbf, outsb, cst, Wre0, Wre12, bias0, bcat, gxe, gxp, lds);
  else if (layer == 1)
    diag_tile<1>(mt, jt, t, x, hbf, outsb, cst, Wre0, Wre12, bias0, bcat, gxe, gxp, lds);
  else
    diag_tile<2>(mt, jt, t, x, hbf, outsb, cst, Wre0, Wre12, bias0, bcat, gxe, gxp, lds);
}

// ---- decoder: logits[b,t,v] = outs[t,b,:] . Wdec[v,:] + b_dec[v]
__global__ __launch_bounds__(256)
void k_decode(const u16* __restrict__ outs, const u16* __restrict__ Wdec,
              const float* __restrict__ bdec, float* __restrict__ logits){
  const int lane = threadIdx.x & 63, w = threadIdx.x >> 6;
  const int cl = lane & 15, ko = (lane >> 4)*8;
  const size_t m0 = ((size_t)blockIdx.x*4 + w)*16;
  const u16* ap = outs + (m0+cl)*1024 + ko;
  f32x4 acc[3];
  #pragma unroll
  for (int nt=0; nt<3; ++nt) acc[nt] = (f32x4){0.f,0.f,0.f,0.f};
  const u16* bp = Wdec + (size_t)cl*1024 + ko;
  for (int k0=0; k0<1024; k0+=32){
    bf16x8 a = *(const bf16x8*)(ap + k0);
    #pragma unroll
    for (int nt=0; nt<3; ++nt){
      bf16x8 b = *(const bf16x8*)(bp + (size_t)nt*16*1024 + k0);
      acc[nt] = MFMA16(a, b, acc[nt]);
    }
  }
  const int rbase = (lane >> 4)*4;
  #pragma unroll
  for (int nt=0; nt<3; ++nt){
    #pragma unroll
    for (int q=0; q<4; ++q){
      int v = nt*16 + cl;
      if (v < 47){
        size_t row = m0 + rbase + q;   // row = t*256 + b
        int tt = (int)(row >> 8);
        int b  = (int)(row & 255);
        logits[((size_t)b*99 + tt)*47 + v] = acc[nt][q] + bdec[v];
      }
    }
  }
}

// ---- final hT / cT copy-out
__global__ void k_final(const u16* __restrict__ hb, const float* __restrict__ cst, float* __restrict__ out){
  int i = blockIdx.x*256 + threadIdx.x;
  if (i < 3*256*1024){
    out[1191168 + i]          = bf2f(hb[i]);
    out[1191168 + 786432 + i] = cst[i];
  }
}

extern "C" void kernel_launch(void* const* d_in, const int* in_sizes, int n_in,
                              void* d_out, int out_size, void* d_ws, size_t ws_size,
                              hipStream_t stream) {
  (void)in_sizes; (void)n_in; (void)out_size; (void)ws_size;
  const int*   x      = (const int*)  d_in[0];
  const float* props  = (const float*)d_in[1];
  const float* h0     = (const float*)d_in[2];
  const float* c0     = (const float*)d_in[3];
  const float* E      = (const float*)d_in[4];
  const float* W_ih0  = (const float*)d_in[5];
  const float* W_hh0  = (const float*)d_in[6];
  const float* b_ih0  = (const float*)d_in[7];
  const float* b_hh0  = (const float*)d_in[8];
  const float* W_ih_r = (const float*)d_in[9];
  const float* W_hh_r = (const float*)d_in[10];
  const float* b_ih_r = (const float*)d_in[11];
  const float* b_hh_r = (const float*)d_in[12];
  const float* W_dec  = (const float*)d_in[13];
  const float* b_dec  = (const float*)d_in[14];
  float* out = (float*)d_out;

  // workspace layout (~110 MB)
  u16* Wre0  = (u16*)d_ws;                          // 4096*1024   (gate-interleaved L0)
  u16* Wre12 = Wre0  + (size_t)4096*1024;           // 2*4096*2048 (gate-interleaved L1/2)
  u16* Wdec  = Wre12 + (size_t)2*4096*2048;         // 48*1024 (row 47 = 0)
  u16* Wih0b = Wdec  + (size_t)48*1024;             // 4096*1024 (first 1024 cols of W_ih0)
  u16* Ebf   = Wih0b + (size_t)4096*1024;           // 48*1024 (row 47 = 0)
  u16* hbf   = Ebf   + (size_t)48*1024;             // 2 * 3*256*1024 (dbuf h, bf16)
  u16* outsb = hbf   + (size_t)2*3*256*1024;        // 99*256*1024
  float* gxe   = (float*)(outsb + (size_t)99*256*1024); // 47*4096
  float* gxp   = gxe   + (size_t)47*4096;               // 256*4096
  float* bias0 = gxp   + (size_t)256*4096;              // 4096
  float* bcat  = bias0 + 4096;                          // 2*4096
  float* cst   = bcat  + 2*4096;                        // 3*256*1024 f32

  // ---- prep
  k_repack0 <<<2048, 256, 0, stream>>>(W_hh0, Wre0);
  k_repack12<<<8192, 256, 0, stream>>>(W_ih_r, W_hh_r, Wre12);
  k_conv<<<2048, 256, 0, stream>>>(W_ih0,  Wih0b, (long)4096*1024, 1024, 1027, 1024, 0);
  k_conv<<<24,   256, 0, stream>>>(E,      Ebf,   (long)47*1024,   1024, 1024, 1024, 0);
  k_conv<<<24,   256, 0, stream>>>(W_dec,  Wdec,  (long)47*1024,   1024, 1024, 1024, 0);
  k_misc<<<7221, 256, 0, stream>>>(b_ih0, b_hh0, b_ih_r, b_hh_r, h0, c0, props, W_ih0,
                                   Ebf, Wdec, bias0, bcat, hbf, cst, gxp);
  k_gxemb<<<dim3(3,256), 64, 0, stream>>>(Ebf, Wih0b, gxe);

  // ---- diagonal recurrence: dispatch d runs (L0@d, L1@d-1, L2@d-2)
  for (int d = 0; d < 101; ++d){
    k_diag<<<384, 256, 0, stream>>>(d, x, hbf, outsb, cst,
                                    Wre0, Wre12, bias0, bcat, gxe, gxp);
  }

  // ---- decode + final states (last write at t=98 -> state buffer 1)
  k_decode<<<396, 256, 0, stream>>>(outsb, Wdec, b_dec, out);
  k_final<<<3072, 256, 0, stream>>>(hbf + (size_t)3*256*1024, cst, out);
}